// Round 1
// baseline (109.330 us; speedup 1.0000x reference)
//
#include <hip/hip_runtime.h>

// RSNA loss: pred/label [128, 8192, 10] fp32, seq_lens [128] i32 -> scalar fp32.
//
// Structure:
//   kernel 1 (128 rows x SPLIT blocks, 256 thr): masked-prefix row sums ->
//     20 floats per row (sum pred[1..9], sum label[1..9], sum y0, sum bce0),
//     float atomicAdd into d_ws (zeroed via hipMemsetAsync).
//   kernel 2 (1 block, 128 thr): per-row nonlinear part (exam BCE of means,
//     image weighting) + final reduction + division -> d_out[0].
//
// Only l < seq_lens[b] is ever read -> ~half the 84 MB input traffic.

#define L_DIM 8192
#define B_DIM 128
#define C_DIM 10
#define SPLIT 8

#define IMAGE_WEIGHT 0.0736196319f

__device__ __constant__ float EXAM_W[9] = {
    0.0736196319f, 0.09202453988f, 0.1042944785f, 0.1042944785f,
    0.1877300613f, 0.06257668712f, 0.06257668712f, 0.2346625767f,
    0.0782208589f};

__global__ __launch_bounds__(256) void rsna_partial_kernel(
    const float* __restrict__ pred, const float* __restrict__ label,
    const int* __restrict__ seq_lens, float* __restrict__ row_acc) {
  const int b = blockIdx.x;  // 0..127
  const int s = blockIdx.y;  // 0..SPLIT-1
  const int len = seq_lens[b];
  const int chunk = (len + SPLIT - 1) / SPLIT;
  const int start = s * chunk;
  const int end = min(start + chunk, len);

  float sp[9], sl[9];
#pragma unroll
  for (int c = 0; c < 9; ++c) {
    sp[c] = 0.0f;
    sl[c] = 0.0f;
  }
  float sy0 = 0.0f;
  float sbce = 0.0f;

  for (int l = start + (int)threadIdx.x; l < end; l += 256) {
    const size_t base = ((size_t)b * L_DIM + (size_t)l) * C_DIM;
    // 40-byte record, 8-byte aligned -> 5x float2 each.
    const float2* p2 = reinterpret_cast<const float2*>(pred + base);
    const float2* y2 = reinterpret_cast<const float2*>(label + base);
    float p[10], y[10];
#pragma unroll
    for (int i = 0; i < 5; ++i) {
      float2 pv = p2[i];
      float2 yv = y2[i];
      p[2 * i] = pv.x;
      p[2 * i + 1] = pv.y;
      y[2 * i] = yv.x;
      y[2 * i + 1] = yv.y;
    }
#pragma unroll
    for (int c = 0; c < 9; ++c) {
      sp[c] += p[c + 1];
      sl[c] += y[c + 1];
    }
    sy0 += y[0];
    sbce += -(y[0] * __logf(p[0]) + (1.0f - y[0]) * __logf(1.0f - p[0]));
  }

  // Pack the 20 per-thread partials and reduce across the block.
  float vals[20];
#pragma unroll
  for (int c = 0; c < 9; ++c) {
    vals[c] = sp[c];
    vals[9 + c] = sl[c];
  }
  vals[18] = sy0;
  vals[19] = sbce;

#pragma unroll
  for (int i = 0; i < 20; ++i) {
    float v = vals[i];
#pragma unroll
    for (int off = 32; off > 0; off >>= 1) v += __shfl_down(v, off, 64);
    vals[i] = v;
  }

  __shared__ float lds[4][20];
  const int wave = threadIdx.x >> 6;
  const int lane = threadIdx.x & 63;
  if (lane == 0) {
#pragma unroll
    for (int i = 0; i < 20; ++i) lds[wave][i] = vals[i];
  }
  __syncthreads();
  if (threadIdx.x < 20) {
    const float v = lds[0][threadIdx.x] + lds[1][threadIdx.x] +
                    lds[2][threadIdx.x] + lds[3][threadIdx.x];
    atomicAdd(&row_acc[b * 20 + (int)threadIdx.x], v);
  }
}

__global__ __launch_bounds__(128) void rsna_final_kernel(
    const float* __restrict__ row_acc, const int* __restrict__ seq_lens,
    float* __restrict__ out) {
  const int b = threadIdx.x;  // 0..127
  const float* r = row_acc + b * 20;
  const float len = (float)seq_lens[b];
  const float inv_len = 1.0f / len;

  float exam = 0.0f;
#pragma unroll
  for (int c = 0; c < 9; ++c) {
    const float pm = r[c] * inv_len;
    const float ym = r[9 + c] * inv_len;
    const float bce = -(ym * __logf(pm) + (1.0f - ym) * __logf(1.0f - pm));
    exam += EXAM_W[c] * bce;
  }
  const float sy0 = r[18];
  const float sbce = r[19];
  const float img_w = IMAGE_WEIGHT * sy0 * inv_len;  // IMAGE_WEIGHT * mean(y0)
  float numer = exam + sbce * img_w;                 // row's loss contribution
  float wext = IMAGE_WEIGHT * sy0;                   // img_w * len

#pragma unroll
  for (int off = 32; off > 0; off >>= 1) {
    numer += __shfl_down(numer, off, 64);
    wext += __shfl_down(wext, off, 64);
  }

  __shared__ float lds[4];
  if ((threadIdx.x & 63) == 0) {
    const int wave = threadIdx.x >> 6;
    lds[wave * 2] = numer;
    lds[wave * 2 + 1] = wext;
  }
  __syncthreads();
  if (threadIdx.x == 0) {
    float wsum = 0.0f;
#pragma unroll
    for (int c = 0; c < 9; ++c) wsum += EXAM_W[c];
    const float n = lds[0] + lds[2];
    const float w = lds[1] + lds[3];
    out[0] = n / ((float)B_DIM * wsum + w);
  }
}

extern "C" void kernel_launch(void* const* d_in, const int* in_sizes, int n_in,
                              void* d_out, int out_size, void* d_ws,
                              size_t ws_size, hipStream_t stream) {
  const float* pred = (const float*)d_in[0];
  const float* label = (const float*)d_in[1];
  const int* seq_lens = (const int*)d_in[2];
  float* row_acc = (float*)d_ws;  // 128*20 floats = 10240 B

  hipMemsetAsync(d_ws, 0, B_DIM * 20 * sizeof(float), stream);

  dim3 grid(B_DIM, SPLIT);
  rsna_partial_kernel<<<grid, 256, 0, stream>>>(pred, label, seq_lens, row_acc);
  rsna_final_kernel<<<1, 128, 0, stream>>>(row_acc, seq_lens, (float*)d_out);
}